// Round 1
// baseline (1798.866 us; speedup 1.0000x reference)
//
#include <hip/hip_runtime.h>

#define S2    0.70710678118654752f   // 1/sqrt(2)
#define S3    0.57735026918962576f   // 1/sqrt(3)
#define FAN   0.027950849718747373f  // 1/sqrt(128*10)
#define RSQ8  0.35355339059327378f   // 1/sqrt(8)
#define RSQ20 0.22360679774997896f   // 1/sqrt(20)

__device__ __forceinline__ float silu_f(float v) {
    return v / (1.0f + __expf(-v));
}

// ---------------- sc (node skip-connection) kernel ----------------
// sc0[n,k] = fan * sum_u x0[n,u] * sw0[u, v(n), k]
// sc1[n,k,m] = fan * sum_u x1[n,u,m] * sw1[u, v(n), k]
// out layout per node: [sc0 (128), sc1 k*3+m (384)]
__global__ __launch_bounds__(512) void sc_kernel(
    const float* __restrict__ na, const float* __restrict__ nf,
    const float* __restrict__ sw0, const float* __restrict__ sw1,
    float* __restrict__ out_sc)
{
    __shared__ float xls[512];
    __shared__ int vcls;
    const int n = blockIdx.x;
    const int t = threadIdx.x;
    xls[t] = nf[(size_t)n * 512 + t];
    if (t < 10 && na[n * 10 + t] > 0.5f) vcls = t;
    __syncthreads();
    const int v = vcls;
    float acc = 0.0f;
    if (t < 128) {
        const float* W = sw0 + v * 128 + t;   // index (u*10+v)*128 + k
        #pragma unroll 8
        for (int u = 0; u < 128; ++u) acc += xls[u] * W[(size_t)u * 1280];
    } else {
        const int q = t - 128;
        const int c = q / 3;
        const int m = q - 3 * c;
        const float* W = sw1 + v * 128 + c;
        #pragma unroll 8
        for (int u = 0; u < 128; ++u) acc += xls[128 + u * 3 + m] * W[(size_t)u * 1280];
    }
    out_sc[(size_t)n * 512 + t] = acc * FAN;
}

// ---------------- fused edge kernel ----------------
// Per 32-edge tile: early MLP layers -> h3 concat (32x128 in LDS),
// final-layer GEMM (128 -> 512) in registers, message epilogue + atomic scatter.
__global__ __launch_bounds__(512) void edge_kernel(
    const float* __restrict__ nf, const float* __restrict__ ea,
    const float* __restrict__ ef, const float* __restrict__ xin,
    const float* __restrict__ w10, const float* __restrict__ w11,
    const float* __restrict__ w12, const float* __restrict__ w13,
    const float* __restrict__ w20, const float* __restrict__ w21,
    const float* __restrict__ w22, const float* __restrict__ w23,
    const int* __restrict__ eidx, float* __restrict__ bases, int E)
{
    __shared__ float hs[32][128];
    __shared__ float htA[8][64];
    __shared__ float htB[8][64];
    const int t = threadIdx.x;
    const int tile = blockIdx.x * 32;

    // ---- phase 1: early MLP layers, 8 groups of 64 threads, 4 iterations ----
    const int g = t >> 6, j = t & 63;
    for (int iter = 0; iter < 4; ++iter) {
        const int el = iter * 8 + g;
        const int e = tile + el;
        float acc = 0.f;
        #pragma unroll
        for (int i = 0; i < 8; ++i) acc += ef[(size_t)e * 8 + i] * w10[i * 64 + j];
        htA[g][j] = silu_f(acc * RSQ8);
        __syncthreads();
        acc = 0.f;
        #pragma unroll 8
        for (int i = 0; i < 64; ++i) acc += htA[g][i] * w11[i * 64 + j];
        htB[g][j] = silu_f(acc * 0.125f);
        __syncthreads();
        acc = 0.f;
        #pragma unroll 8
        for (int i = 0; i < 64; ++i) acc += htB[g][i] * w12[i * 64 + j];
        hs[el][j] = silu_f(acc * 0.125f);
        // mlp2 (writes htA only after the post-l1a barrier above)
        acc = 0.f;
        #pragma unroll
        for (int i = 0; i < 20; ++i) acc += xin[(size_t)e * 20 + i] * w20[i * 64 + j];
        htA[g][j] = silu_f(acc * RSQ20);
        __syncthreads();
        acc = 0.f;
        #pragma unroll 8
        for (int i = 0; i < 64; ++i) acc += htA[g][i] * w21[i * 64 + j];
        htB[g][j] = silu_f(acc * 0.125f);
        __syncthreads();
        acc = 0.f;
        #pragma unroll 8
        for (int i = 0; i < 64; ++i) acc += htB[g][i] * w22[i * 64 + j];
        hs[el][64 + j] = silu_f(acc * 0.125f);
        __syncthreads();
    }

    // ---- phase 2: w[e,k] = 0.125 * sum_i hs[e][i] * W3cat[i][k] ----
    // thread owns channel c=kq and the 4 quadrants k = c, c+128, c+256, c+384
    // for 8 edges (eg*8 .. eg*8+7).
    const int kq = t & 127;
    const int eg = t >> 7;
    float aA[8], aB[8], aC[8], aD[8];
    #pragma unroll
    for (int ee = 0; ee < 8; ++ee) { aA[ee] = aB[ee] = aC[ee] = aD[ee] = 0.f; }
    for (int i4 = 0; i4 < 32; ++i4) {
        float4 hv[8];
        #pragma unroll
        for (int ee = 0; ee < 8; ++ee)
            hv[ee] = *(const float4*)&hs[eg * 8 + ee][i4 * 4];
        #pragma unroll
        for (int ii = 0; ii < 4; ++ii) {
            const int i = i4 * 4 + ii;
            const float* W3 = (i < 64) ? (w13 + (size_t)i * 512)
                                       : (w23 + (size_t)(i - 64) * 512);
            const float wA = W3[kq], wB = W3[kq + 128],
                        wC = W3[kq + 256], wD = W3[kq + 384];
            #pragma unroll
            for (int ee = 0; ee < 8; ++ee) {
                const float hvv = ((const float*)&hv[ee])[ii];
                aA[ee] += hvv * wA;
                aB[ee] += hvv * wB;
                aC[ee] += hvv * wC;
                aD[ee] += hvv * wD;
            }
        }
    }

    // ---- phase 3: message + atomic scatter into bases ----
    const int c = kq;
    #pragma unroll 2
    for (int ee = 0; ee < 8; ++ee) {
        const int el = eg * 8 + ee;
        const int e = tile + el;
        const int s = eidx[e];
        const int r = eidx[E + e];
        const float y0  = ea[(size_t)e * 4 + 0];
        const float y1a = ea[(size_t)e * 4 + 1];
        const float y1b = ea[(size_t)e * 4 + 2];
        const float y1c = ea[(size_t)e * 4 + 3];
        const float* nfr = nf + (size_t)s * 512;
        const float xs0 = nfr[c];
        const float x1a = nfr[128 + 3 * c], x1b = nfr[129 + 3 * c], x1c = nfr[130 + 3 * c];
        const float wa = aA[ee] * 0.125f, wb = aB[ee] * 0.125f;
        const float wcv = aC[ee] * 0.125f, wd = aD[ee] * 0.125f;
        const float dot = x1a * y1a + x1b * y1b + x1c * y1c;
        float* br = bases + (size_t)r * 512;
        atomicAdd(&br[c],               S2 * 0.1f * (wa * xs0 * y0 + wd * dot * S3));
        atomicAdd(&br[128 + 3 * c + 0], S2 * 0.1f * (wb * xs0 * y1a + wcv * x1a * y0));
        atomicAdd(&br[128 + 3 * c + 1], S2 * 0.1f * (wb * xs0 * y1b + wcv * x1b * y0));
        atomicAdd(&br[128 + 3 * c + 2], S2 * 0.1f * (wb * xs0 * y1c + wcv * x1c * y0));
    }
}

extern "C" void kernel_launch(void* const* d_in, const int* in_sizes, int n_in,
                              void* d_out, int out_size, void* d_ws, size_t ws_size,
                              hipStream_t stream) {
    // setup_inputs() dict order:
    // 0 node_attrs, 1 node_feats, 2 edge_attrs, 3 edge_feats, 4 x,
    // 5 edge_index, 6 node_num,
    // 7 mlp1_w0, 8 mlp2_w0, 9 mlp1_w1, 10 mlp2_w1, 11 mlp1_w2, 12 mlp2_w2,
    // 13 mlp1_w3, 14 mlp2_w3, 15 skip_w0, 16 skip_w1
    const float* na  = (const float*)d_in[0];
    const float* nf  = (const float*)d_in[1];
    const float* ea  = (const float*)d_in[2];
    const float* ef  = (const float*)d_in[3];
    const float* xin = (const float*)d_in[4];
    const int*   eidx= (const int*)d_in[5];
    const float* w10 = (const float*)d_in[7];
    const float* w20 = (const float*)d_in[8];
    const float* w11 = (const float*)d_in[9];
    const float* w21 = (const float*)d_in[10];
    const float* w12 = (const float*)d_in[11];
    const float* w22 = (const float*)d_in[12];
    const float* w13 = (const float*)d_in[13];
    const float* w23 = (const float*)d_in[14];
    const float* sw0 = (const float*)d_in[15];
    const float* sw1 = (const float*)d_in[16];

    const int N = in_sizes[1] / 512;
    const int E = in_sizes[2] / 4;

    float* bases  = (float*)d_out;
    float* out_sc = (float*)d_out + (size_t)N * 512;

    // bases accumulated via atomics -> must zero every launch
    hipMemsetAsync(bases, 0, (size_t)N * 512 * sizeof(float), stream);

    sc_kernel<<<N, 512, 0, stream>>>(na, nf, sw0, sw1, out_sc);
    edge_kernel<<<E / 32, 512, 0, stream>>>(nf, ea, ef, xin,
                                            w10, w11, w12, w13,
                                            w20, w21, w22, w23,
                                            eidx, bases, E);
}

// Round 2
// 1573.802 us; speedup vs baseline: 1.1430x; 1.1430x over previous
//
#include <hip/hip_runtime.h>
#include <hip/hip_bf16.h>

#define S2    0.70710678118654752f   // 1/sqrt(2)
#define S3    0.57735026918962576f   // 1/sqrt(3)
#define FAN   0.027950849718747373f  // 1/sqrt(128*10)
#define RSQ8  0.35355339059327378f   // 1/sqrt(8)
#define RSQ20 0.22360679774997896f   // 1/sqrt(20)

typedef __attribute__((ext_vector_type(8))) short bf16x8;
typedef __attribute__((ext_vector_type(4))) float f32x4;

__device__ __forceinline__ float silu_f(float v) {
    return v / (1.0f + __expf(-v));
}

// ---------------- sc (node skip-connection) kernel ----------------
__global__ __launch_bounds__(512) void sc_kernel(
    const float* __restrict__ na, const float* __restrict__ nf,
    const float* __restrict__ sw0, const float* __restrict__ sw1,
    float* __restrict__ out_sc)
{
    __shared__ float xls[512];
    __shared__ int vcls;
    const int n = blockIdx.x;
    const int t = threadIdx.x;
    xls[t] = nf[(size_t)n * 512 + t];
    if (t < 10 && na[n * 10 + t] > 0.5f) vcls = t;
    __syncthreads();
    const int v = vcls;
    float acc = 0.0f;
    if (t < 128) {
        const float* W = sw0 + v * 128 + t;   // (u*10+v)*128 + k
        #pragma unroll 8
        for (int u = 0; u < 128; ++u) acc += xls[u] * W[(size_t)u * 1280];
    } else {
        const int q = t - 128;
        const int c = q / 3;
        const int m = q - 3 * c;
        const float* W = sw1 + v * 128 + c;
        #pragma unroll 8
        for (int u = 0; u < 128; ++u) acc += xls[128 + u * 3 + m] * W[(size_t)u * 1280];
    }
    out_sc[(size_t)n * 512 + t] = acc * FAN;
}

// ---------------- W3 pre-convert: fp32 [128][512] -> bf16 B-fragments ----------------
// B-fragment layout for mfma_f32_16x16x32_bf16:
//   lane l holds B[k=(l>>4)*8+j][col=(l&15)] for j=0..7, per (n-tile nt, k-step ks).
// Stored as bfrag[((nt*4+ks)*64 + l)*8 + j]. 1/sqrt(64)=0.125 folded in.
__global__ __launch_bounds__(256) void conv_w3_kernel(
    const float* __restrict__ w13, const float* __restrict__ w23,
    ushort* __restrict__ bfrag)
{
    const int idx = blockIdx.x * 256 + threadIdx.x;  // 8192 total
    const int l  = idx & 63;
    const int ks = (idx >> 6) & 3;
    const int nt = idx >> 8;
    const int col = nt * 16 + (l & 15);
    const int k0  = ks * 32 + (l >> 4) * 8;
    #pragma unroll
    for (int j = 0; j < 8; ++j) {
        const int k = k0 + j;
        const float v = (k < 64) ? w13[(size_t)k * 512 + col]
                                 : w23[(size_t)(k - 64) * 512 + col];
        __hip_bfloat16 hb = __float2bfloat16(v * 0.125f);
        bfrag[(size_t)idx * 8 + j] = *reinterpret_cast<unsigned short*>(&hb);
    }
}

// swizzled bf16 store into the h3 LDS tile (row el, column col of 128)
__device__ __forceinline__ void store_h(ushort* hs, int el, int col, float v) {
    __hip_bfloat16 hb = __float2bfloat16(v);
    const unsigned short us = *reinterpret_cast<unsigned short*>(&hb);
    *(ushort*)((char*)hs + el * 256 + ((col * 2) ^ ((el & 7) << 4))) = us;
}

// ---------------- fused edge kernel ----------------
__global__ __launch_bounds__(512) void edge_kernel(
    const float* __restrict__ nf, const float* __restrict__ ea,
    const float* __restrict__ ef, const float* __restrict__ xin,
    const float* __restrict__ w10, const float* __restrict__ w11,
    const float* __restrict__ w12,
    const float* __restrict__ w20, const float* __restrict__ w21,
    const float* __restrict__ w22,
    const ushort* __restrict__ bfrag,
    const int* __restrict__ eidx, float* __restrict__ bases, int E)
{
    __shared__ ushort hs[32 * 128];      // h3 concat, bf16, XOR-swizzled rows
    __shared__ float htA[8][64];
    __shared__ float htB[8][64];
    const int t = threadIdx.x;
    const int tile = blockIdx.x * 32;

    // ---- phase 1: early MLP layers (fp32 VALU), 8 waves x 4 iterations ----
    const int g = t >> 6, j = t & 63;
    for (int iter = 0; iter < 4; ++iter) {
        const int el = iter * 8 + g;
        const int e = tile + el;
        float acc = 0.f;
        #pragma unroll
        for (int i = 0; i < 8; ++i) acc += ef[(size_t)e * 8 + i] * w10[i * 64 + j];
        htA[g][j] = silu_f(acc * RSQ8);
        __syncthreads();
        acc = 0.f;
        #pragma unroll 8
        for (int i = 0; i < 64; ++i) acc += htA[g][i] * w11[i * 64 + j];
        htB[g][j] = silu_f(acc * 0.125f);
        __syncthreads();
        acc = 0.f;
        #pragma unroll 8
        for (int i = 0; i < 64; ++i) acc += htB[g][i] * w12[i * 64 + j];
        store_h(hs, el, j, silu_f(acc * 0.125f));
        // mlp2
        acc = 0.f;
        #pragma unroll
        for (int i = 0; i < 20; ++i) acc += xin[(size_t)e * 20 + i] * w20[i * 64 + j];
        htA[g][j] = silu_f(acc * RSQ20);
        __syncthreads();
        acc = 0.f;
        #pragma unroll 8
        for (int i = 0; i < 64; ++i) acc += htA[g][i] * w21[i * 64 + j];
        htB[g][j] = silu_f(acc * 0.125f);
        __syncthreads();
        acc = 0.f;
        #pragma unroll 8
        for (int i = 0; i < 64; ++i) acc += htB[g][i] * w22[i * 64 + j];
        store_h(hs, el, 64 + j, silu_f(acc * 0.125f));
        __syncthreads();
    }

    // ---- phase 2: w = h3 @ W3cat via bf16 MFMA ----
    // wave w owns n-tiles {q*8+w}, q=0..3 -> quadrants A,B,C,D of channels
    // [w*16, w*16+16). acc[mt][q] : D rows = edges mt*16 + (l>>4)*4 + r.
    const int wv = t >> 6;
    const int l  = t & 63;
    const int hi = l >> 4, lo = l & 15;

    f32x4 acc2[2][4];
    #pragma unroll
    for (int mt = 0; mt < 2; ++mt)
        #pragma unroll
        for (int q = 0; q < 4; ++q) acc2[mt][q] = (f32x4){0.f, 0.f, 0.f, 0.f};

    const char* hp = (const char*)hs;
    const bf16x8* bfv = (const bf16x8*)bfrag;
    #pragma unroll
    for (int ks = 0; ks < 4; ++ks) {
        bf16x8 afr[2];
        #pragma unroll
        for (int mt = 0; mt < 2; ++mt) {
            const int row = mt * 16 + lo;
            afr[mt] = *(const bf16x8*)(hp + row * 256 +
                        ((ks * 64 + hi * 16) ^ ((lo & 7) << 4)));
        }
        #pragma unroll
        for (int q = 0; q < 4; ++q) {
            const bf16x8 bfr = bfv[((q * 8 + wv) * 4 + ks) * 64 + l];
            #pragma unroll
            for (int mt = 0; mt < 2; ++mt)
                acc2[mt][q] = __builtin_amdgcn_mfma_f32_16x16x32_bf16(
                    afr[mt], bfr, acc2[mt][q], 0, 0, 0);
        }
    }

    // ---- phase 3: message + atomic scatter ----
    const int c = wv * 16 + lo;
    #pragma unroll
    for (int mt = 0; mt < 2; ++mt) {
        #pragma unroll
        for (int r = 0; r < 4; ++r) {
            const int el = mt * 16 + hi * 4 + r;
            const int e = tile + el;
            const int s  = eidx[e];
            const int rr = eidx[E + e];
            const float4 yv = *(const float4*)&ea[(size_t)e * 4];
            const float y0 = yv.x, y1a = yv.y, y1b = yv.z, y1c = yv.w;
            const float* nfr = nf + (size_t)s * 512;
            const float xs0 = nfr[c];
            const float x1a = nfr[128 + 3 * c], x1b = nfr[129 + 3 * c],
                        x1c = nfr[130 + 3 * c];
            const float wa = acc2[mt][0][r], wb = acc2[mt][1][r];
            const float wcv = acc2[mt][2][r], wd = acc2[mt][3][r];
            const float dot = x1a * y1a + x1b * y1b + x1c * y1c;
            float* br = bases + (size_t)rr * 512;
            atomicAdd(&br[c],               S2 * 0.1f * (wa * xs0 * y0 + wd * dot * S3));
            atomicAdd(&br[128 + 3 * c + 0], S2 * 0.1f * (wb * xs0 * y1a + wcv * x1a * y0));
            atomicAdd(&br[128 + 3 * c + 1], S2 * 0.1f * (wb * xs0 * y1b + wcv * x1b * y0));
            atomicAdd(&br[128 + 3 * c + 2], S2 * 0.1f * (wb * xs0 * y1c + wcv * x1c * y0));
        }
    }
}

extern "C" void kernel_launch(void* const* d_in, const int* in_sizes, int n_in,
                              void* d_out, int out_size, void* d_ws, size_t ws_size,
                              hipStream_t stream) {
    const float* na  = (const float*)d_in[0];
    const float* nf  = (const float*)d_in[1];
    const float* ea  = (const float*)d_in[2];
    const float* ef  = (const float*)d_in[3];
    const float* xin = (const float*)d_in[4];
    const int*   eidx= (const int*)d_in[5];
    const float* w10 = (const float*)d_in[7];
    const float* w20 = (const float*)d_in[8];
    const float* w11 = (const float*)d_in[9];
    const float* w21 = (const float*)d_in[10];
    const float* w12 = (const float*)d_in[11];
    const float* w22 = (const float*)d_in[12];
    const float* w13 = (const float*)d_in[13];
    const float* w23 = (const float*)d_in[14];
    const float* sw0 = (const float*)d_in[15];
    const float* sw1 = (const float*)d_in[16];

    const int N = in_sizes[1] / 512;
    const int E = in_sizes[2] / 4;

    float* bases  = (float*)d_out;
    float* out_sc = (float*)d_out + (size_t)N * 512;
    ushort* bfrag = (ushort*)d_ws;   // 128 KB of B-fragments

    // bases accumulated via atomics -> must zero every launch
    hipMemsetAsync(bases, 0, (size_t)N * 512 * sizeof(float), stream);

    conv_w3_kernel<<<32, 256, 0, stream>>>(w13, w23, bfrag);
    sc_kernel<<<N, 512, 0, stream>>>(na, nf, sw0, sw1, out_sc);
    edge_kernel<<<E / 32, 512, 0, stream>>>(nf, ea, ef, xin,
                                            w10, w11, w12,
                                            w20, w21, w22,
                                            bfrag, eidx, bases, E);
}